// Round 5
// baseline (976.495 us; speedup 1.0000x reference)
//
#include <hip/hip_runtime.h>
#include <math.h>

#define NB 32
#define NN 512
#define DD 256
#define NROW  (NB*NN)      // 16384 rows per input
#define NELEM (NB*NN*DD)   // 4194304 elements per input

constexpr float INV_EPS   = 10.0f;
constexpr float F_TINY    = 1e-16f;
constexpr float F_NORMEPS = 1e-8f;
constexpr float MARG      = 1.0f / 512.0f;   // a = b = 1/n

typedef __attribute__((ext_vector_type(8))) short bf16x8;
typedef __attribute__((ext_vector_type(4))) float f32x4;

__device__ __forceinline__ unsigned short f2bf(float f) {
    unsigned u = __float_as_uint(f);
    u += 0x7fffu + ((u >> 16) & 1u);          // round-to-nearest-even
    return (unsigned short)(u >> 16);
}
__device__ __forceinline__ float bf2f(unsigned short h) {
    return __uint_as_float(((unsigned)h) << 16);
}

// ---------------------------------------------------------------------------
// Fused: row norms of x,y  +  hi/lo bf16 split  +  zero cost.
// One wave per row (256 floats, float4/lane). 8192 blocks x 256.
// ---------------------------------------------------------------------------
__global__ __launch_bounds__(256) void norms_convert(
        const float* __restrict__ x, const float* __restrict__ y,
        float* __restrict__ nx, float* __restrict__ ny,
        unsigned short* __restrict__ xh, unsigned short* __restrict__ xl,
        unsigned short* __restrict__ yh, unsigned short* __restrict__ yl,
        float* __restrict__ cost) {
    if (blockIdx.x == 0 && threadIdx.x < NB) cost[threadIdx.x] = 0.0f;
    int w = threadIdx.x >> 6, l = threadIdx.x & 63;
    int row = blockIdx.x * 4 + w;             // 0..32767
    bool isx = row < NROW;
    int r = isx ? row : row - NROW;
    const float* src = (isx ? x : y) + (size_t)r * DD;
    float4 v = ((const float4*)src)[l];
    float ss = v.x * v.x + v.y * v.y + v.z * v.z + v.w * v.w;
#pragma unroll
    for (int off = 32; off; off >>= 1) ss += __shfl_xor(ss, off);

    unsigned short h0 = f2bf(v.x), h1 = f2bf(v.y), h2 = f2bf(v.z), h3 = f2bf(v.w);
    unsigned short l0 = f2bf(v.x - bf2f(h0)), l1 = f2bf(v.y - bf2f(h1));
    unsigned short l2 = f2bf(v.z - bf2f(h2)), l3 = f2bf(v.w - bf2f(h3));
    unsigned short* ph = (isx ? xh : yh) + (size_t)r * DD + l * 4;
    unsigned short* pl = (isx ? xl : yl) + (size_t)r * DD + l * 4;
    *(ushort4*)ph = make_ushort4(h0, h1, h2, h3);
    *(ushort4*)pl = make_ushort4(l0, l1, l2, l3);

    if (l == 0) (isx ? nx : ny)[r] = sqrtf(ss);
}

// ---------------------------------------------------------------------------
// C[b,n,m] = 1 - <x_n,y_m>/max(|x_n||y_m|, 1e-8)  via bf16 MFMA, hi/lo split:
// dot = xh.yh + xh.yl + xl.yh  (fp32-grade).  128x128 tile, BK=32, 256 thr.
// LDS: 64B rows, chunk XOR-swizzle (pc = c ^ ((row>>1)&3)) -> <=2-way conflicts.
// ---------------------------------------------------------------------------
__global__ __launch_bounds__(256) void gemm_cos_mfma(
        const unsigned short* __restrict__ xh, const unsigned short* __restrict__ xl,
        const unsigned short* __restrict__ yh, const unsigned short* __restrict__ yl,
        const float* __restrict__ nx, const float* __restrict__ ny,
        float* __restrict__ C) {
    int blk = blockIdx.x;
    int b = blk >> 4, ti = (blk >> 2) & 3, tj = blk & 3;
    __shared__ short Ah[128][32], Al[128][32], Bh[128][32], Bl[128][32];
    const unsigned short* xbh = xh + ((size_t)b * NN + ti * 128) * DD;
    const unsigned short* xbl = xl + ((size_t)b * NN + ti * 128) * DD;
    const unsigned short* ybh = yh + ((size_t)b * NN + tj * 128) * DD;
    const unsigned short* ybl = yl + ((size_t)b * NN + tj * 128) * DD;
    int t = threadIdx.x, w = t >> 6, l = t & 63;
    int rw = w * 32, q = l >> 4, low = l & 15;

    f32x4 acc[2][8];
#pragma unroll
    for (int i = 0; i < 2; ++i)
#pragma unroll
        for (int j = 0; j < 8; ++j) acc[i][j] = (f32x4){0.f, 0.f, 0.f, 0.f};

    int sr = t >> 1, h = t & 1;               // staging: 2 threads/row
    int c0i = 2 * h, c1i = 2 * h + 1;         // logical 16B chunks
    int sw0 = (c0i ^ ((sr >> 1) & 3)) * 8;    // swizzled short offsets
    int sw1 = (c1i ^ ((sr >> 1) & 3)) * 8;

    for (int k0 = 0; k0 < DD; k0 += 32) {
        {
            const int4* ga = (const int4*)(xbh + (size_t)sr * DD + k0);
            const int4* gb = (const int4*)(xbl + (size_t)sr * DD + k0);
            const int4* gc = (const int4*)(ybh + (size_t)sr * DD + k0);
            const int4* gd = (const int4*)(ybl + (size_t)sr * DD + k0);
            int4 a0 = ga[c0i], a1 = ga[c1i];
            int4 b0 = gb[c0i], b1 = gb[c1i];
            int4 c0 = gc[c0i], c1 = gc[c1i];
            int4 d0 = gd[c0i], d1 = gd[c1i];
            *(int4*)&Ah[sr][sw0] = a0; *(int4*)&Ah[sr][sw1] = a1;
            *(int4*)&Al[sr][sw0] = b0; *(int4*)&Al[sr][sw1] = b1;
            *(int4*)&Bh[sr][sw0] = c0; *(int4*)&Bh[sr][sw1] = c1;
            *(int4*)&Bl[sr][sw0] = d0; *(int4*)&Bl[sr][sw1] = d1;
        }
        __syncthreads();

        bf16x8 ah[2], al[2];
#pragma unroll
        for (int ti2 = 0; ti2 < 2; ++ti2) {
            int m = rw + ti2 * 16 + low;
            int pq = (q ^ ((m >> 1) & 3)) * 8;
            ah[ti2] = *(const bf16x8*)&Ah[m][pq];
            al[ti2] = *(const bf16x8*)&Al[m][pq];
        }
#pragma unroll
        for (int tj2 = 0; tj2 < 8; ++tj2) {
            int n = tj2 * 16 + low;
            int pq = (q ^ ((n >> 1) & 3)) * 8;
            bf16x8 bh = *(const bf16x8*)&Bh[n][pq];
            bf16x8 bl = *(const bf16x8*)&Bl[n][pq];
#pragma unroll
            for (int ti2 = 0; ti2 < 2; ++ti2) {
                f32x4 a = acc[ti2][tj2];
                a = __builtin_amdgcn_mfma_f32_16x16x32_bf16(ah[ti2], bh, a, 0, 0, 0);
                a = __builtin_amdgcn_mfma_f32_16x16x32_bf16(ah[ti2], bl, a, 0, 0, 0);
                a = __builtin_amdgcn_mfma_f32_16x16x32_bf16(al[ti2], bh, a, 0, 0, 0);
                acc[ti2][tj2] = a;
            }
        }
        __syncthreads();
    }

    // epilogue: C/D layout col=lane&15, row=(lane>>4)*4+reg  [m89-corrected]
    float* Cb = C + (size_t)b * NN * NN;
#pragma unroll
    for (int ti2 = 0; ti2 < 2; ++ti2) {
#pragma unroll
        for (int tj2 = 0; tj2 < 8; ++tj2) {
            int gm0 = ti * 128 + rw + ti2 * 16 + q * 4;
            int gn  = tj * 128 + tj2 * 16 + low;
            float nyc = ny[b * NN + gn];
            f32x4 a = acc[ti2][tj2];
#pragma unroll
            for (int reg = 0; reg < 4; ++reg) {
                int gm = gm0 + reg;
                float d = 1.0f - a[reg] / fmaxf(nx[b * NN + gm] * nyc, F_NORMEPS);
                Cb[(size_t)gm * NN + gn] = d;
            }
        }
    }
}

// ---------------------------------------------------------------------------
// All 15 Sinkhorn iterations: ONE BLOCK PER BATCH (1024 thr = 16 waves).
// E = exp(-C/eps) register-resident: wave owns 32 rows, lane owns 8 cols
// ({4l..4l+3, 256+4l..4l+3}) -> E[32][8] = 256 VGPRs. All reductions are
// block-local: row sums via 6 shuffles, col sums via 16-wave LDS tree.
// Zero cross-block communication, zero atomics, plain __syncthreads.
// ---------------------------------------------------------------------------
__global__ __launch_bounds__(1024) void sink_all(
        const float* __restrict__ C, float* __restrict__ P,
        float* __restrict__ Q) {
    int b = blockIdx.x;
    int t = threadIdx.x, w = t >> 6, l = t & 63;
    int rw = w * 32;

    __shared__ float sW[NN];              // w_m = B_m * v_m
    __shared__ float sBB[NN];             // B_m
    __shared__ float sWP[16][NN];         // per-wave column partials (32 KB)

    // ---- load E stripe (32 rows x 8 owned cols) into registers
    float E[32][8];
    const float* Cb = C + ((size_t)b * NN + rw) * NN;
#pragma unroll
    for (int i = 0; i < 32; ++i) {
        const float* row = Cb + (size_t)i * NN;
        float4 a = *(const float4*)(row + 4 * l);
        float4 c = *(const float4*)(row + 256 + 4 * l);
        E[i][0] = __expf(-INV_EPS * a.x); E[i][1] = __expf(-INV_EPS * a.y);
        E[i][2] = __expf(-INV_EPS * a.z); E[i][3] = __expf(-INV_EPS * a.w);
        E[i][4] = __expf(-INV_EPS * c.x); E[i][5] = __expf(-INV_EPS * c.y);
        E[i][6] = __expf(-INV_EPS * c.z); E[i][7] = __expf(-INV_EPS * c.w);
    }
    float A[32];
#pragma unroll
    for (int i = 0; i < 32; ++i) A[i] = 1.0f;
    if (t < NN) { sW[t] = 1.0f; sBB[t] = 1.0f; }
    __syncthreads();

#pragma unroll 1
    for (int it = 0; it < 15; ++it) {
        // ---- phase A: u for own 32 rows (full butterfly -> A replicated)
        float wr[8];
        *(float4*)&wr[0] = *(const float4*)&sW[4 * l];
        *(float4*)&wr[4] = *(const float4*)&sW[256 + 4 * l];
#pragma unroll
        for (int i = 0; i < 32; ++i) {
            float s = 0.0f;
#pragma unroll
            for (int e = 0; e < 8; ++e) s = fmaf(E[i][e], wr[e], s);
#pragma unroll
            for (int off = 32; off; off >>= 1) s += __shfl_xor(s, off);
            float uu = MARG / (A[i] * s + F_TINY);
            A[i] *= uu;
            if (it == 14 && l == 0)
                P[b * NN + rw + i] = A[i] * uu;   // P_n = A_15 * u_15
        }

        // ---- phase B: column partials over own 32 rows
        float p[8];
#pragma unroll
        for (int e = 0; e < 8; ++e) {
            float s = 0.0f;
#pragma unroll
            for (int i = 0; i < 32; ++i) s = fmaf(E[i][e], A[i], s);
            p[e] = s;
        }
        *(float4*)&sWP[w][4 * l]       = make_float4(p[0], p[1], p[2], p[3]);
        *(float4*)&sWP[w][256 + 4 * l] = make_float4(p[4], p[5], p[6], p[7]);
        __syncthreads();

        // ---- phase C: finish v for all 512 cols (threads 0..511)
        if (t < NN) {
            float sv = 0.0f;
#pragma unroll
            for (int ww = 0; ww < 16; ++ww) sv += sWP[ww][t];
            float Bc = sBB[t];
            float vv = MARG / (Bc * sv + F_TINY);
            Bc *= vv;
            sBB[t] = Bc;
            sW[t]  = Bc * vv;             // next u-weight = B_new * v
        }
        __syncthreads();
    }

    // ---- Q_m = B_15 * v_15 (= sW)
    if (t < NN) Q[b * NN + t] = sW[t];
}

// ---------------------------------------------------------------------------
// pi = P_n * Q_m * exp(-C/eps);  cost_b = sum pi*C
// ---------------------------------------------------------------------------
__global__ __launch_bounds__(256) void pi_cost(
        const float* __restrict__ C, const float* __restrict__ P,
        const float* __restrict__ Q, float* __restrict__ pi,
        float* __restrict__ cost) {
    int b = blockIdx.x >> 4, rg = blockIdx.x & 15;
    __shared__ float sQ[NN];
    __shared__ float sPart[4];
    for (int i = threadIdx.x; i < NN; i += 256) sQ[i] = Q[b * NN + i];
    __syncthreads();
    int w = threadIdx.x >> 6, l = threadIdx.x & 63;
    float q0[8];
    *(float4*)&q0[0] = *(const float4*)&sQ[4 * l];
    *(float4*)&q0[4] = *(const float4*)&sQ[256 + 4 * l];
    const float* Cb = C + (size_t)b * NN * NN;
    float* pib = pi + (size_t)b * NN * NN;
    float csum = 0.0f;
#pragma unroll 1
    for (int i = 0; i < 8; ++i) {
        int r = rg * 32 + w * 8 + i;
        float pf = P[b * NN + r];
        const float* crow = Cb + (size_t)r * NN;
        float* prow = pib + (size_t)r * NN;
        float4 c0 = *(const float4*)(crow + 4 * l);
        float4 c1 = *(const float4*)(crow + 256 + 4 * l);
        float pv0 = pf * q0[0] * __expf(-INV_EPS * c0.x);
        float pv1 = pf * q0[1] * __expf(-INV_EPS * c0.y);
        float pv2 = pf * q0[2] * __expf(-INV_EPS * c0.z);
        float pv3 = pf * q0[3] * __expf(-INV_EPS * c0.w);
        float pv4 = pf * q0[4] * __expf(-INV_EPS * c1.x);
        float pv5 = pf * q0[5] * __expf(-INV_EPS * c1.y);
        float pv6 = pf * q0[6] * __expf(-INV_EPS * c1.z);
        float pv7 = pf * q0[7] * __expf(-INV_EPS * c1.w);
        *(float4*)(prow + 4 * l)       = make_float4(pv0, pv1, pv2, pv3);
        *(float4*)(prow + 256 + 4 * l) = make_float4(pv4, pv5, pv6, pv7);
        csum = fmaf(pv0, c0.x, csum); csum = fmaf(pv1, c0.y, csum);
        csum = fmaf(pv2, c0.z, csum); csum = fmaf(pv3, c0.w, csum);
        csum = fmaf(pv4, c1.x, csum); csum = fmaf(pv5, c1.y, csum);
        csum = fmaf(pv6, c1.z, csum); csum = fmaf(pv7, c1.w, csum);
    }
#pragma unroll
    for (int off = 32; off; off >>= 1) csum += __shfl_xor(csum, off);
    if (l == 0) sPart[w] = csum;
    __syncthreads();
    if (threadIdx.x == 0) {
        float tot = sPart[0] + sPart[1] + sPart[2] + sPart[3];
        atomicAdd(&cost[b], tot);
    }
}

// ---------------------------------------------------------------------------
extern "C" void kernel_launch(void* const* d_in, const int* in_sizes, int n_in,
                              void* d_out, int out_size, void* d_ws, size_t ws_size,
                              hipStream_t stream) {
    const float* x = (const float*)d_in[0];
    const float* y = (const float*)d_in[1];
    float* out  = (float*)d_out;
    float* cost = out;                                   // [32]
    float* pi   = out + 32;                              // [32*512*512]
    float* C    = out + 32 + (size_t)NB * NN * NN;       // [32*512*512]

    float* ws = (float*)d_ws;
    float* nx = ws;                    // 16384
    float* ny = ws + 16384;            // 16384
    float* P  = ws + 32768;            // 16384
    float* Q  = ws + 49152;            // 16384

    // bf16 hi/lo arrays live in the pi region (exactly 4*NELEM*2B = pi bytes);
    // dead after gemm; pi rewritten at the very end.
    unsigned short* xh = (unsigned short*)pi;
    unsigned short* xl = xh + NELEM;
    unsigned short* yh = xl + NELEM;
    unsigned short* yl = yh + NELEM;

    norms_convert<<<dim3(8192), dim3(256), 0, stream>>>(
        x, y, nx, ny, xh, xl, yh, yl, cost);
    gemm_cos_mfma<<<dim3(512), dim3(256), 0, stream>>>(
        xh, xl, yh, yl, nx, ny, C);
    sink_all<<<dim3(32), dim3(1024), 0, stream>>>(C, P, Q);
    pi_cost<<<dim3(512), dim3(256), 0, stream>>>(C, P, Q, pi, cost);
}

// Round 6
// 206.898 us; speedup vs baseline: 4.7197x; 4.7197x over previous
//
#include <hip/hip_runtime.h>
#include <hip/hip_fp16.h>
#include <math.h>

#define NB 32
#define NN 512
#define DD 256
#define NROW  (NB*NN)      // 16384 rows per input
#define NELEM (NB*NN*DD)   // 4194304 elements per input

constexpr float INV_EPS   = 10.0f;
constexpr float F_TINY    = 1e-16f;
constexpr float F_NORMEPS = 1e-8f;
constexpr float MARG      = 1.0f / 512.0f;   // a = b = 1/n

typedef __attribute__((ext_vector_type(8))) short bf16x8;
typedef __attribute__((ext_vector_type(4))) float f32x4;

__device__ __forceinline__ unsigned short f2bf(float f) {
    unsigned u = __float_as_uint(f);
    u += 0x7fffu + ((u >> 16) & 1u);          // round-to-nearest-even
    return (unsigned short)(u >> 16);
}

// ---------------------------------------------------------------------------
// Fused: row norms of x,y + bf16 convert + zero cost.
// One wave per row (256 floats, float4/lane). 8192 blocks x 256.
// ---------------------------------------------------------------------------
__global__ __launch_bounds__(256) void norms_convert(
        const float* __restrict__ x, const float* __restrict__ y,
        float* __restrict__ nx, float* __restrict__ ny,
        unsigned short* __restrict__ xh, unsigned short* __restrict__ yh,
        float* __restrict__ cost) {
    if (blockIdx.x == 0 && threadIdx.x < NB) cost[threadIdx.x] = 0.0f;
    int w = threadIdx.x >> 6, l = threadIdx.x & 63;
    int row = blockIdx.x * 4 + w;             // 0..32767
    bool isx = row < NROW;
    int r = isx ? row : row - NROW;
    const float* src = (isx ? x : y) + (size_t)r * DD;
    float4 v = ((const float4*)src)[l];
    float ss = v.x * v.x + v.y * v.y + v.z * v.z + v.w * v.w;
#pragma unroll
    for (int off = 32; off; off >>= 1) ss += __shfl_xor(ss, off);

    unsigned short* ph = (isx ? xh : yh) + (size_t)r * DD + l * 4;
    *(ushort4*)ph = make_ushort4(f2bf(v.x), f2bf(v.y), f2bf(v.z), f2bf(v.w));
    if (l == 0) (isx ? nx : ny)[r] = sqrtf(ss);
}

// ---------------------------------------------------------------------------
// C[b,n,m] = 1 - <x_n,y_m>/max(|x_n||y_m|, 1e-8), single bf16 MFMA.
// Fused epilogue also writes E = fp16(exp(-C/eps)).
// 128x128 tile, BK=32, 256 thr. XOR-swizzled LDS (verified in R4).
// ---------------------------------------------------------------------------
__global__ __launch_bounds__(256) void gemm_cos_mfma(
        const unsigned short* __restrict__ xh, const unsigned short* __restrict__ yh,
        const float* __restrict__ nx, const float* __restrict__ ny,
        float* __restrict__ C, __half* __restrict__ Ef) {
    int blk = blockIdx.x;
    int b = blk >> 4, ti = (blk >> 2) & 3, tj = blk & 3;
    __shared__ short Ah[128][32], Bh[128][32];
    const unsigned short* xbh = xh + ((size_t)b * NN + ti * 128) * DD;
    const unsigned short* ybh = yh + ((size_t)b * NN + tj * 128) * DD;
    int t = threadIdx.x, w = t >> 6, l = t & 63;
    int rw = w * 32, q = l >> 4, low = l & 15;

    f32x4 acc[2][8];
#pragma unroll
    for (int i = 0; i < 2; ++i)
#pragma unroll
        for (int j = 0; j < 8; ++j) acc[i][j] = (f32x4){0.f, 0.f, 0.f, 0.f};

    int sr = t >> 1, h = t & 1;               // staging: 2 threads/row
    int c0i = 2 * h, c1i = 2 * h + 1;         // logical 16B chunks
    int sw0 = (c0i ^ ((sr >> 1) & 3)) * 8;    // swizzled short offsets
    int sw1 = (c1i ^ ((sr >> 1) & 3)) * 8;

    for (int k0 = 0; k0 < DD; k0 += 32) {
        {
            const int4* ga = (const int4*)(xbh + (size_t)sr * DD + k0);
            const int4* gc = (const int4*)(ybh + (size_t)sr * DD + k0);
            int4 a0 = ga[c0i], a1 = ga[c1i];
            int4 c0 = gc[c0i], c1 = gc[c1i];
            *(int4*)&Ah[sr][sw0] = a0; *(int4*)&Ah[sr][sw1] = a1;
            *(int4*)&Bh[sr][sw0] = c0; *(int4*)&Bh[sr][sw1] = c1;
        }
        __syncthreads();

        bf16x8 ah[2];
#pragma unroll
        for (int ti2 = 0; ti2 < 2; ++ti2) {
            int m = rw + ti2 * 16 + low;
            int pq = (q ^ ((m >> 1) & 3)) * 8;
            ah[ti2] = *(const bf16x8*)&Ah[m][pq];
        }
#pragma unroll
        for (int tj2 = 0; tj2 < 8; ++tj2) {
            int n = tj2 * 16 + low;
            int pq = (q ^ ((n >> 1) & 3)) * 8;
            bf16x8 bh = *(const bf16x8*)&Bh[n][pq];
#pragma unroll
            for (int ti2 = 0; ti2 < 2; ++ti2)
                acc[ti2][tj2] = __builtin_amdgcn_mfma_f32_16x16x32_bf16(
                    ah[ti2], bh, acc[ti2][tj2], 0, 0, 0);
        }
        __syncthreads();
    }

    // epilogue: C/D layout col=lane&15, row=(lane>>4)*4+reg  [m89-corrected]
    float*  Cb = C  + (size_t)b * NN * NN;
    __half* Eb = Ef + (size_t)b * NN * NN;
#pragma unroll
    for (int ti2 = 0; ti2 < 2; ++ti2) {
#pragma unroll
        for (int tj2 = 0; tj2 < 8; ++tj2) {
            int gm0 = ti * 128 + rw + ti2 * 16 + q * 4;
            int gn  = tj * 128 + tj2 * 16 + low;
            float nyc = ny[b * NN + gn];
            f32x4 a = acc[ti2][tj2];
#pragma unroll
            for (int reg = 0; reg < 4; ++reg) {
                int gm = gm0 + reg;
                float d = 1.0f - a[reg] / fmaxf(nx[b * NN + gm] * nyc, F_NORMEPS);
                Cb[(size_t)gm * NN + gn] = d;
                Eb[(size_t)gm * NN + gn] = __float2half(__expf(-INV_EPS * d));
            }
        }
    }
}

// ---------------------------------------------------------------------------
// One Sinkhorn iteration per launch (t = 1..15), stream-order barrier.
// Reads precomputed fp16 E (L2-resident: 512KB/batch, 4 batches/XCD).
// Block = 64-row stripe of one batch (8 blocks/batch, XCD-swizzled).
// Lane owns cols {8l..8l+7} (one 16B fp16 load per row).
// ---------------------------------------------------------------------------
__global__ __launch_bounds__(512) void sink_iter(
        const __half* __restrict__ Ef, const float* __restrict__ cp_prev,
        float* __restrict__ cp_cur, float* __restrict__ A_g,
        const float* __restrict__ B_rd, float* __restrict__ B_wr,
        float* __restrict__ P, int t) {
    int blk = blockIdx.x;
    int xcd = blk & 7, qq = blk >> 3;
    int o = qq & 7;                       // stripe slot within batch
    int b = ((qq >> 3) << 3) | xcd;       // batch (8 stripes share blk%8/XCD)
    int blkbase = blk - 8 * o;            // slot-0 block id of this batch
    int tt = threadIdx.x, w = tt >> 6, l = tt & 63;
    int r0 = o * 64 + w * 8;              // wave's first row

    __shared__ float sW[NN];              // w_m = B_m * v_m
    __shared__ float sWP[8][NN];          // per-wave column partials

    // ---- step 1: finish v_{t-1} (t>=2); t==1 has v_0=1, B_0=1
    if (t == 1) {
        sW[tt] = 1.0f;
    } else {
        float sv = 0.0f;
#pragma unroll
        for (int k = 0; k < 8; ++k)
            sv += cp_prev[(size_t)(blkbase + 8 * k) * NN + tt];
        float Bc = (t == 2) ? 1.0f : B_rd[b * NN + tt];
        float vv = MARG / (Bc * sv + F_TINY);
        float Bn = Bc * vv;
        sW[tt] = Bn * vv;
        if (o == 0) B_wr[b * NN + tt] = Bn;
    }

    // ---- load E stripe into registers: lane owns cols 8l..8l+7
    float E[8][8];
    const __half* Eb = Ef + ((size_t)b * NN + r0) * NN + 8 * l;
#pragma unroll
    for (int i = 0; i < 8; ++i) {
        int4 raw = *(const int4*)(Eb + (size_t)i * NN);
        const __half* hv = (const __half*)&raw;
#pragma unroll
        for (int e = 0; e < 8; ++e) E[i][e] = __half2float(hv[e]);
    }
    float A[8];
#pragma unroll
    for (int i = 0; i < 8; ++i)
        A[i] = (t == 1) ? 1.0f : A_g[b * NN + r0 + i];   // broadcast load
    __syncthreads();

    // ---- step 2: u for own 8 rows
    float wr[8];
    *(float4*)&wr[0] = *(const float4*)&sW[8 * l];
    *(float4*)&wr[4] = *(const float4*)&sW[8 * l + 4];
#pragma unroll
    for (int i = 0; i < 8; ++i) {
        float s = 0.0f;
#pragma unroll
        for (int e = 0; e < 8; ++e) s = fmaf(E[i][e], wr[e], s);
#pragma unroll
        for (int off = 32; off; off >>= 1) s += __shfl_xor(s, off);
        float uu = MARG / (A[i] * s + F_TINY);
        A[i] *= uu;
        if (l == 0) {
            if (t == 15) P[b * NN + r0 + i] = A[i] * uu;  // A_15 * u_15
            else         A_g[b * NN + r0 + i] = A[i];
        }
    }

    // ---- step 3: column partials over own stripe with A_t
    float p[8];
#pragma unroll
    for (int e = 0; e < 8; ++e) {
        float s = 0.0f;
#pragma unroll
        for (int i = 0; i < 8; ++i) s = fmaf(E[i][e], A[i], s);
        p[e] = s;
    }
    *(float4*)&sWP[w][8 * l]     = make_float4(p[0], p[1], p[2], p[3]);
    *(float4*)&sWP[w][8 * l + 4] = make_float4(p[4], p[5], p[6], p[7]);
    __syncthreads();
    float cs = 0.0f;
#pragma unroll
    for (int ww = 0; ww < 8; ++ww) cs += sWP[ww][tt];
    cp_cur[(size_t)blk * NN + tt] = cs;
}

// ---------------------------------------------------------------------------
// finish v_15 -> Q_m = B_15*v_15 (one block per batch)
// ---------------------------------------------------------------------------
__global__ __launch_bounds__(512) void finish_q(
        const float* __restrict__ cp, const float* __restrict__ B_rd,
        float* __restrict__ Q) {
    int b = blockIdx.x, tt = threadIdx.x;
    int blkbase = ((b >> 3) << 6) | (b & 7);
    float sv = 0.0f;
#pragma unroll
    for (int k = 0; k < 8; ++k)
        sv += cp[(size_t)(blkbase + 8 * k) * NN + tt];
    float Bc = B_rd[b * NN + tt];
    float vv = MARG / (Bc * sv + F_TINY);
    Q[b * NN + tt] = Bc * vv * vv;     // B_15 * v_15
}

// ---------------------------------------------------------------------------
// pi = P_n * Q_m * exp(-C/eps);  cost_b = sum pi*C
// ---------------------------------------------------------------------------
__global__ __launch_bounds__(256) void pi_cost(
        const float* __restrict__ C, const float* __restrict__ P,
        const float* __restrict__ Q, float* __restrict__ pi,
        float* __restrict__ cost) {
    int b = blockIdx.x >> 4, rg = blockIdx.x & 15;
    __shared__ float sQ[NN];
    __shared__ float sPart[4];
    for (int i = threadIdx.x; i < NN; i += 256) sQ[i] = Q[b * NN + i];
    __syncthreads();
    int w = threadIdx.x >> 6, l = threadIdx.x & 63;
    float q0[8];
    *(float4*)&q0[0] = *(const float4*)&sQ[4 * l];
    *(float4*)&q0[4] = *(const float4*)&sQ[256 + 4 * l];
    const float* Cb = C + (size_t)b * NN * NN;
    float* pib = pi + (size_t)b * NN * NN;
    float csum = 0.0f;
#pragma unroll 1
    for (int i = 0; i < 8; ++i) {
        int r = rg * 32 + w * 8 + i;
        float pf = P[b * NN + r];
        const float* crow = Cb + (size_t)r * NN;
        float* prow = pib + (size_t)r * NN;
        float4 c0 = *(const float4*)(crow + 4 * l);
        float4 c1 = *(const float4*)(crow + 256 + 4 * l);
        float pv0 = pf * q0[0] * __expf(-INV_EPS * c0.x);
        float pv1 = pf * q0[1] * __expf(-INV_EPS * c0.y);
        float pv2 = pf * q0[2] * __expf(-INV_EPS * c0.z);
        float pv3 = pf * q0[3] * __expf(-INV_EPS * c0.w);
        float pv4 = pf * q0[4] * __expf(-INV_EPS * c1.x);
        float pv5 = pf * q0[5] * __expf(-INV_EPS * c1.y);
        float pv6 = pf * q0[6] * __expf(-INV_EPS * c1.z);
        float pv7 = pf * q0[7] * __expf(-INV_EPS * c1.w);
        *(float4*)(prow + 4 * l)       = make_float4(pv0, pv1, pv2, pv3);
        *(float4*)(prow + 256 + 4 * l) = make_float4(pv4, pv5, pv6, pv7);
        csum = fmaf(pv0, c0.x, csum); csum = fmaf(pv1, c0.y, csum);
        csum = fmaf(pv2, c0.z, csum); csum = fmaf(pv3, c0.w, csum);
        csum = fmaf(pv4, c1.x, csum); csum = fmaf(pv5, c1.y, csum);
        csum = fmaf(pv6, c1.z, csum); csum = fmaf(pv7, c1.w, csum);
    }
#pragma unroll
    for (int off = 32; off; off >>= 1) csum += __shfl_xor(csum, off);
    if (l == 0) sPart[w] = csum;
    __syncthreads();
    if (threadIdx.x == 0) {
        float tot = sPart[0] + sPart[1] + sPart[2] + sPart[3];
        atomicAdd(&cost[b], tot);
    }
}

// ---------------------------------------------------------------------------
extern "C" void kernel_launch(void* const* d_in, const int* in_sizes, int n_in,
                              void* d_out, int out_size, void* d_ws, size_t ws_size,
                              hipStream_t stream) {
    const float* x = (const float*)d_in[0];
    const float* y = (const float*)d_in[1];
    float* out  = (float*)d_out;
    float* cost = out;                                   // [32]
    float* pi   = out + 32;                              // [32*512*512]
    float* C    = out + 32 + (size_t)NB * NN * NN;       // [32*512*512]

    float* ws = (float*)d_ws;
    float* nx = ws;                    // 16384
    float* ny = ws + 16384;            // 16384
    float* P  = ws + 32768;            // 16384
    float* Q  = ws + 49152;            // 16384
    float* A  = ws + 65536;            // 16384
    float* Bb[2] = { ws + 81920, ws + 98304 };   // ping-pong B (16384 each)

    // pi region reuse (33.55 MB):
    //   [xh: 8.4 MB][yh: 8.4 MB][Ef16: 16.8 MB]
    // xh/yh dead after gemm; cp double-buffer (1 MB) lives in xh region.
    // pi itself rewritten only at the very end (after finish_q).
    unsigned short* xh = (unsigned short*)pi;
    unsigned short* yh = xh + NELEM;
    __half* Ef = (__half*)(yh + NELEM);
    float* cp[2] = { pi, pi + 256 * NN };

    norms_convert<<<dim3(8192), dim3(256), 0, stream>>>(
        x, y, nx, ny, xh, yh, cost);
    gemm_cos_mfma<<<dim3(512), dim3(256), 0, stream>>>(
        xh, yh, nx, ny, C, Ef);

    for (int t = 1; t <= 15; ++t) {
        // launch t: reads B_{t-2} from Bb[t&1], writes B_{t-1} to Bb[(t-1)&1]
        sink_iter<<<dim3(256), dim3(512), 0, stream>>>(
            Ef, cp[(t - 1) & 1], cp[t & 1], A,
            Bb[t & 1], Bb[(t - 1) & 1], P, t);
    }
    // cp_15 is in cp[1]; B_14 is in Bb[0]
    finish_q<<<dim3(32), dim3(512), 0, stream>>>(cp[1], Bb[0], Q);
    pi_cost<<<dim3(512), dim3(256), 0, stream>>>(C, P, Q, pi, cost);
}